// Round 9
// baseline (228.631 us; speedup 1.0000x reference)
//
#include <hip/hip_runtime.h>
#include <hip/hip_cooperative_groups.h>
#include <hip/hip_bf16.h>
#include <math.h>

namespace cg = cooperative_groups;

// B=8, T=128, D=512. M = 1024 rows, N = 6*512 = 3072 concatenated outputs.
// R9: ONE cooperative kernel, 384 blocks x 256 threads, two grid.sync()s.
//   Phase A: split fp32 -> (hi,lo) bf16 packed per 32-K super-chunk.
//   Phase B: software-pipelined bf16 MFMA GEMM (R7 structure, LDS dbuf),
//            C = Ah*Bh + Ah*Bl + Al*Bh.
//   Phase C: fused feature-softmax + temporal Taylor-moment softmax,
//            one wave per row (R6 structure), intra-wave LDS transpose.
// Rationale: every prior fused/convert dispatch carried ~5-15us of
// launch/ramp overhead that no amount of tuning compressed; fusing into
// one launch deletes two dispatch boundaries.

#define M_ROWS 1024
#define DIMD   512
#define NCOLS  3072
#define KPHYS  1024

typedef __attribute__((ext_vector_type(8))) short short8;
typedef __attribute__((ext_vector_type(4))) float f32x4;
typedef __attribute__((ext_vector_type(4))) unsigned short u16x4;

struct PtrArgs {
    const float* W[6];
    const float* b[6];
};

#define XN (M_ROWS * DIMD)
#define WN (NCOLS * DIMD)
#define NV4 ((XN + WN) / 4)      // 524288 vec4 groups
#define NTHREADS (384 * 256)

__device__ __forceinline__ unsigned short bf16_rne(float v) {
    unsigned u = __float_as_uint(v);
    u = (u + 0x7FFFu + ((u >> 16) & 1u)) >> 16;
    return (unsigned short)u;
}

__device__ __constant__ float INVFACT[25] = {
    1.0f, 1.0f, 0.5f,
    1.6666666666666666e-01f, 4.1666666666666664e-02f, 8.3333333333333332e-03f,
    1.3888888888888889e-03f, 1.9841269841269841e-04f, 2.4801587301587302e-05f,
    2.7557319223985893e-06f, 2.7557319223985888e-07f, 2.5052108385441720e-08f,
    2.0876756987868100e-09f, 1.6059043836821613e-10f, 1.1470745597729725e-11f,
    7.6471637318198164e-13f, 4.7794773323873853e-14f, 2.8114572543455206e-15f,
    1.5619206968586225e-16f, 8.2206352466243295e-18f, 4.1103176233121648e-19f,
    1.9572941063391263e-20f, 8.8967913924505741e-22f, 3.8681701706306835e-23f,
    1.6117375710961184e-24f
};

#define PSTR 53
#define PWAVE (64 * PSTR + 56)   // per-wave float count: part + cbuf + pad

union SMem {
    struct {
        short As[2][64 * 64];     // 16 KB
        short Bs[2][128 * 64];    // 32 KB
    } g;
    struct {
        float part[4][PWAVE];     // 4 waves x (64*53 part + 50 cbuf) = 55.2 KB
    } f;
};

__global__ __launch_bounds__(256, 2) void mega(const float* __restrict__ x,
                                               PtrArgs pa,
                                               unsigned short* __restrict__ Aph,
                                               unsigned short* __restrict__ Bph,
                                               float* __restrict__ biasAll,
                                               float* __restrict__ Y,
                                               float* __restrict__ out) {
    cg::grid_group grid = cg::this_grid();
    __shared__ __align__(16) SMem sm;

    const int tid = threadIdx.x;
    const int bid = blockIdx.x;

    // ======================= Phase A: convert/split =======================
    {
        int gtid = bid * 256 + tid;
        if (gtid < NCOLS) biasAll[gtid] = pa.b[gtid >> 9][gtid & 511];
        for (int i = gtid; i < NV4; i += NTHREADS) {
            const int e4 = i * 4;
            if (e4 < XN) {
                int m = e4 >> 9, k = e4 & 511;
                int s = k >> 5, p = k & 31;
                float4 v = *(const float4*)(x + e4);
                u16x4 hi, lo;
                hi.x = bf16_rne(v.x); lo.x = bf16_rne(v.x - __uint_as_float(((unsigned)hi.x) << 16));
                hi.y = bf16_rne(v.y); lo.y = bf16_rne(v.y - __uint_as_float(((unsigned)hi.y) << 16));
                hi.z = bf16_rne(v.z); lo.z = bf16_rne(v.z - __uint_as_float(((unsigned)hi.z) << 16));
                hi.w = bf16_rne(v.w); lo.w = bf16_rne(v.w - __uint_as_float(((unsigned)hi.w) << 16));
                *(u16x4*)&Aph[(size_t)m * KPHYS + s * 64 + p]      = hi;
                *(u16x4*)&Aph[(size_t)m * KPHYS + s * 64 + 32 + p] = lo;
            } else {
                int j = e4 - XN;
                int n = j >> 9, k = j & 511;
                int g = n >> 9, o = n & 511;
                int s = k >> 5, p = k & 31;
                float4 v = *(const float4*)(pa.W[g] + (size_t)o * DIMD + k);
                u16x4 hi, lo;
                hi.x = bf16_rne(v.x); lo.x = bf16_rne(v.x - __uint_as_float(((unsigned)hi.x) << 16));
                hi.y = bf16_rne(v.y); lo.y = bf16_rne(v.y - __uint_as_float(((unsigned)hi.y) << 16));
                hi.z = bf16_rne(v.z); lo.z = bf16_rne(v.z - __uint_as_float(((unsigned)hi.z) << 16));
                hi.w = bf16_rne(v.w); lo.w = bf16_rne(v.w - __uint_as_float(((unsigned)hi.w) << 16));
                *(u16x4*)&Bph[(size_t)n * KPHYS + s * 64 + p]      = hi;
                *(u16x4*)&Bph[(size_t)n * KPHYS + s * 64 + 32 + p] = lo;
            }
        }
    }
    grid.sync();

    // ======================= Phase B: MFMA GEMM ==========================
    {
        const int m0   = (bid / 24) * 64;
        const int n0   = (bid % 24) * 128;
        const int lane = tid & 63;
        const int w    = tid >> 6;
        const int wm   = w & 1;
        const int wn   = w >> 1;
        const int l15  = lane & 15;
        const int quad = lane >> 4;

        f32x4 acc[2][4];
        #pragma unroll
        for (int i = 0; i < 2; ++i)
            #pragma unroll
            for (int j = 0; j < 4; ++j)
                acc[i][j] = (f32x4){0.f, 0.f, 0.f, 0.f};

        auto stage = [&](int it, int buf) {
            const int kbase = it * 64;
            #pragma unroll
            for (int t = 0; t < 2; ++t) {
                int idx = t * 256 + tid;
                int r = idx >> 3, c = idx & 7;
                int cc = c ^ (r & 7);
                const unsigned short* ga = Aph + (size_t)(m0 + r) * KPHYS + kbase + cc * 8;
                __builtin_amdgcn_global_load_lds(
                    (const __attribute__((address_space(1))) unsigned int*)ga,
                    (__attribute__((address_space(3))) unsigned int*)&sm.g.As[buf][idx * 8], 16, 0, 0);
            }
            #pragma unroll
            for (int t = 0; t < 4; ++t) {
                int idx = t * 256 + tid;
                int r = idx >> 3, c = idx & 7;
                int cc = c ^ (r & 7);
                const unsigned short* gb = Bph + (size_t)(n0 + r) * KPHYS + kbase + cc * 8;
                __builtin_amdgcn_global_load_lds(
                    (const __attribute__((address_space(1))) unsigned int*)gb,
                    (__attribute__((address_space(3))) unsigned int*)&sm.g.Bs[buf][idx * 8], 16, 0, 0);
            }
        };

        stage(0, 0);

        for (int it = 0; it < 16; ++it) {
            __syncthreads();
            if (it + 1 < 16) stage(it + 1, (it + 1) & 1);

            const short* as = sm.g.As[it & 1];
            const short* bs = sm.g.Bs[it & 1];
            short8 ah[2], al[2], bh[4], bl[4];
            #pragma unroll
            for (int mt = 0; mt < 2; ++mt) {
                int rA = wm * 32 + mt * 16 + l15;
                int ch = quad ^ (rA & 7);
                int cl = (4 + quad) ^ (rA & 7);
                ah[mt] = *(const short8*)&as[(rA * 8 + ch) * 8];
                al[mt] = *(const short8*)&as[(rA * 8 + cl) * 8];
            }
            #pragma unroll
            for (int nt = 0; nt < 4; ++nt) {
                int rB = wn * 64 + nt * 16 + l15;
                int ch = quad ^ (rB & 7);
                int cl = (4 + quad) ^ (rB & 7);
                bh[nt] = *(const short8*)&bs[(rB * 8 + ch) * 8];
                bl[nt] = *(const short8*)&bs[(rB * 8 + cl) * 8];
            }
            #pragma unroll
            for (int mt = 0; mt < 2; ++mt)
                #pragma unroll
                for (int nt = 0; nt < 4; ++nt) {
                    acc[mt][nt] = __builtin_amdgcn_mfma_f32_16x16x32_bf16(
                        ah[mt], bh[nt], acc[mt][nt], 0, 0, 0);
                    acc[mt][nt] = __builtin_amdgcn_mfma_f32_16x16x32_bf16(
                        ah[mt], bl[nt], acc[mt][nt], 0, 0, 0);
                    acc[mt][nt] = __builtin_amdgcn_mfma_f32_16x16x32_bf16(
                        al[mt], bh[nt], acc[mt][nt], 0, 0, 0);
                }
        }

        // Epilogue. C/D: col = lane&15, row = quad*4 + reg  [m89-verified]
        #pragma unroll
        for (int nt = 0; nt < 4; ++nt) {
            int col = n0 + wn * 64 + nt * 16 + l15;
            float bv = biasAll[col];
            #pragma unroll
            for (int mt = 0; mt < 2; ++mt) {
                int row0 = m0 + wm * 32 + mt * 16 + quad * 4;
                #pragma unroll
                for (int r = 0; r < 4; ++r)
                    Y[(size_t)(row0 + r) * NCOLS + col] = acc[mt][nt][r] + bv;
            }
        }
    }
    grid.sync();

    // ======================= Phase C: fused branches =====================
    // One wave per row; row = wave*384 + bid (balanced, waves 0..2 active).
    // Pure intra-wave: LDS transpose ordering enforced by same-wave lgkmcnt.
    {
        const int w    = tid >> 6;
        const int lane = tid & 63;
        const int row  = w * 384 + bid;
        if (row < M_ROWS) {
            float* part = sm.f.part[w];
            float* cbuf = part + 64 * PSTR;
            const float* __restrict__ Yr = Y + (size_t)row * NCOLS;
            const int i0 = lane * 8;
            const float LOG2E = 1.4426950408889634f;

            float4 qf0 = *(const float4*)(Yr + i0);
            float4 qf1 = *(const float4*)(Yr + i0 + 4);
            float4 kf0 = *(const float4*)(Yr + 512 + i0);
            float4 kf1 = *(const float4*)(Yr + 512 + i0 + 4);
            float4 vf0 = *(const float4*)(Yr + 1024 + i0);
            float4 vf1 = *(const float4*)(Yr + 1024 + i0 + 4);
            float4 qt0 = *(const float4*)(Yr + 1536 + i0);
            float4 qt1 = *(const float4*)(Yr + 1536 + i0 + 4);
            float4 kt0 = *(const float4*)(Yr + 2048 + i0);
            float4 kt1 = *(const float4*)(Yr + 2048 + i0 + 4);
            float4 vt0 = *(const float4*)(Yr + 2560 + i0);
            float4 vt1 = *(const float4*)(Yr + 2560 + i0 + 4);

            float e[8];
            e[0] = __builtin_amdgcn_exp2f(qf0.x * kf0.x * LOG2E);
            e[1] = __builtin_amdgcn_exp2f(qf0.y * kf0.y * LOG2E);
            e[2] = __builtin_amdgcn_exp2f(qf0.z * kf0.z * LOG2E);
            e[3] = __builtin_amdgcn_exp2f(qf0.w * kf0.w * LOG2E);
            e[4] = __builtin_amdgcn_exp2f(qf1.x * kf1.x * LOG2E);
            e[5] = __builtin_amdgcn_exp2f(qf1.y * kf1.y * LOG2E);
            e[6] = __builtin_amdgcn_exp2f(qf1.z * kf1.z * LOG2E);
            e[7] = __builtin_amdgcn_exp2f(qf1.w * kf1.w * LOG2E);
            float psum = ((e[0] + e[1]) + (e[2] + e[3])) + ((e[4] + e[5]) + (e[6] + e[7]));
            #pragma unroll
            for (int off = 32; off; off >>= 1) psum += __shfl_xor(psum, off);
            const float invS = 1.0f / psum;

            float k[8] = {kt0.x, kt0.y, kt0.z, kt0.w, kt1.x, kt1.y, kt1.z, kt1.w};
            float v[8] = {vt0.x, vt0.y, vt0.z, vt0.w, vt1.x, vt1.y, vt1.z, vt1.w};
            float kp[8] = {1.f, 1.f, 1.f, 1.f, 1.f, 1.f, 1.f, 1.f};
            float* myrow = &part[lane * PSTR];
            #pragma unroll
            for (int p = 0; p < 25; ++p) {
                float n = ((kp[0] + kp[1]) + (kp[2] + kp[3])) +
                          ((kp[4] + kp[5]) + (kp[6] + kp[7]));
                float m = fmaf(kp[7], v[7], fmaf(kp[6], v[6],
                          fmaf(kp[5], v[5], fmaf(kp[4], v[4],
                          fmaf(kp[3], v[3], fmaf(kp[2], v[2],
                          fmaf(kp[1], v[1], kp[0] * v[0])))))));
                myrow[p]      = m;
                myrow[25 + p] = n;
                #pragma unroll
                for (int j = 0; j < 8; ++j) kp[j] *= k[j];
            }
            // intra-wave: ds_writes above ordered before ds_reads below

            if (lane < 50) {
                float s = 0.f;
                #pragma unroll
                for (int i = 0; i < 64; ++i) s += part[i * PSTR + lane];
                cbuf[lane] = s * INVFACT[lane < 25 ? lane : lane - 25];
            }

            float q[8] = {qt0.x, qt0.y, qt0.z, qt0.w, qt1.x, qt1.y, qt1.z, qt1.w};
            float F[8], G[8];
            {
                float cf = cbuf[24], cg = cbuf[49];
                #pragma unroll
                for (int c = 0; c < 8; ++c) { F[c] = cf; G[c] = cg; }
            }
            #pragma unroll
            for (int p = 23; p >= 0; --p) {
                float cf = cbuf[p], cg = cbuf[25 + p];
                #pragma unroll
                for (int c = 0; c < 8; ++c) {
                    F[c] = fmaf(F[c], q[c], cf);
                    G[c] = fmaf(G[c], q[c], cg);
                }
            }

            float4 o0, o1;
            o0.x = e[0] * invS * vf0.x + F[0] / G[0];
            o0.y = e[1] * invS * vf0.y + F[1] / G[1];
            o0.z = e[2] * invS * vf0.z + F[2] / G[2];
            o0.w = e[3] * invS * vf0.w + F[3] / G[3];
            o1.x = e[4] * invS * vf1.x + F[4] / G[4];
            o1.y = e[5] * invS * vf1.y + F[5] / G[5];
            o1.z = e[6] * invS * vf1.z + F[6] / G[6];
            o1.w = e[7] * invS * vf1.w + F[7] / G[7];
            *(float4*)(out + (size_t)row * DIMD + i0)     = o0;
            *(float4*)(out + (size_t)row * DIMD + i0 + 4) = o1;
        }
    }
}

extern "C" void kernel_launch(void* const* d_in, const int* in_sizes, int n_in,
                              void* d_out, int out_size, void* d_ws, size_t ws_size,
                              hipStream_t stream) {
    const float* x = (const float*)d_in[0];
    PtrArgs pa;
    for (int g = 0; g < 6; ++g) {
        pa.W[g] = (const float*)d_in[1 + 2 * g];
        pa.b[g] = (const float*)d_in[2 + 2 * g];
    }

    // Workspace layout:
    //   Y:    [1024][3072] fp32  = 12,582,912 B
    //   Aph:  [1024][1024] bf16  =  2,097,152 B
    //   Bph:  [3072][1024] bf16  =  6,291,456 B
    //   bias: [3072] fp32        =     12,288 B
    char* ws = (char*)d_ws;
    float*          Y    = (float*)ws;
    unsigned short* Aph  = (unsigned short*)(ws + 12582912);
    unsigned short* Bph  = (unsigned short*)(ws + 12582912 + 2097152);
    float*          bias = (float*)(ws + 12582912 + 2097152 + 6291456);
    float*          out  = (float*)d_out;

    void* args[] = {(void*)&x, (void*)&pa, (void*)&Aph, (void*)&Bph,
                    (void*)&bias, (void*)&Y, (void*)&out};
    hipLaunchCooperativeKernel((const void*)mega, dim3(384), dim3(256),
                               args, 0, stream);
}

// Round 10
// 107.196 us; speedup vs baseline: 2.1328x; 2.1328x over previous
//
#include <hip/hip_runtime.h>
#include <hip/hip_bf16.h>
#include <math.h>

// B=8, T=128, D=512. M = 1024 rows, N = 6*512 = 3072 concatenated outputs.
// Stage 0: split fp32 -> (hi,lo) bf16, packed per 32-K super-chunk.
// Stage 1: software-pipelined bf16 MFMA GEMM (R7 dbuf structure).
//          R10: XCD-aware block swizzle — each XCD (bid&7) owns 3 n-tiles
//          x 16 m-tiles, so every 262KB Bph n-tile is read 16x from ONE
//          XCD's L2 instead of 8 XCDs re-fetching through L3 (100MB->6MB).
// Stage 2: fused branches via degree-24 Taylor moments (R6 wave-per-row).
// R9's cooperative mega-kernel REVERTED: grid.sync() cost ~50us each.

#define M_ROWS 1024
#define DIMD   512
#define NCOLS  3072
#define KPHYS  1024

typedef __attribute__((ext_vector_type(8))) short short8;
typedef __attribute__((ext_vector_type(4))) float f32x4;
typedef __attribute__((ext_vector_type(4))) unsigned short u16x4;

struct PtrArgs {
    const float* W[6];
    const float* b[6];
};

#define XN (M_ROWS * DIMD)
#define WN (NCOLS * DIMD)

__device__ __forceinline__ unsigned short bf16_rne(float v) {
    unsigned u = __float_as_uint(v);
    u = (u + 0x7FFFu + ((u >> 16) & 1u)) >> 16;
    return (unsigned short)u;
}

__device__ __constant__ float INVFACT[25] = {
    1.0f, 1.0f, 0.5f,
    1.6666666666666666e-01f, 4.1666666666666664e-02f, 8.3333333333333332e-03f,
    1.3888888888888889e-03f, 1.9841269841269841e-04f, 2.4801587301587302e-05f,
    2.7557319223985893e-06f, 2.7557319223985888e-07f, 2.5052108385441720e-08f,
    2.0876756987868100e-09f, 1.6059043836821613e-10f, 1.1470745597729725e-11f,
    7.6471637318198164e-13f, 4.7794773323873853e-14f, 2.8114572543455206e-15f,
    1.5619206968586225e-16f, 8.2206352466243295e-18f, 4.1103176233121648e-19f,
    1.9572941063391263e-20f, 8.8967913924505741e-22f, 3.8681701706306835e-23f,
    1.6117375710961184e-24f
};

// ---------------------------------------------------------------------------
// Stage 0: convert/split, float4-vectorized (unchanged from R7).
// ---------------------------------------------------------------------------
__global__ __launch_bounds__(256) void convert_split(const float* __restrict__ x,
                                                     PtrArgs pa,
                                                     unsigned short* __restrict__ Aph,
                                                     unsigned short* __restrict__ Bph,
                                                     float* __restrict__ biasAll) {
    const int idx = blockIdx.x * 256 + threadIdx.x;   // vec4 index
    if (idx < NCOLS) {
        biasAll[idx] = pa.b[idx >> 9][idx & 511];
    }
    const int e4 = idx * 4;
    if (e4 < XN) {
        int m = e4 >> 9, k = e4 & 511;
        int s = k >> 5, p = k & 31;
        float4 v = *(const float4*)(x + e4);
        u16x4 hi, lo;
        hi.x = bf16_rne(v.x); lo.x = bf16_rne(v.x - __uint_as_float(((unsigned)hi.x) << 16));
        hi.y = bf16_rne(v.y); lo.y = bf16_rne(v.y - __uint_as_float(((unsigned)hi.y) << 16));
        hi.z = bf16_rne(v.z); lo.z = bf16_rne(v.z - __uint_as_float(((unsigned)hi.z) << 16));
        hi.w = bf16_rne(v.w); lo.w = bf16_rne(v.w - __uint_as_float(((unsigned)hi.w) << 16));
        *(u16x4*)&Aph[(size_t)m * KPHYS + s * 64 + p]      = hi;
        *(u16x4*)&Aph[(size_t)m * KPHYS + s * 64 + 32 + p] = lo;
    } else if (e4 < XN + WN) {
        int j = e4 - XN;
        int n = j >> 9, k = j & 511;
        int g = n >> 9, o = n & 511;
        int s = k >> 5, p = k & 31;
        float4 v = *(const float4*)(pa.W[g] + (size_t)o * DIMD + k);
        u16x4 hi, lo;
        hi.x = bf16_rne(v.x); lo.x = bf16_rne(v.x - __uint_as_float(((unsigned)hi.x) << 16));
        hi.y = bf16_rne(v.y); lo.y = bf16_rne(v.y - __uint_as_float(((unsigned)hi.y) << 16));
        hi.z = bf16_rne(v.z); lo.z = bf16_rne(v.z - __uint_as_float(((unsigned)hi.z) << 16));
        hi.w = bf16_rne(v.w); lo.w = bf16_rne(v.w - __uint_as_float(((unsigned)hi.w) << 16));
        *(u16x4*)&Bph[(size_t)n * KPHYS + s * 64 + p]      = hi;
        *(u16x4*)&Bph[(size_t)n * KPHYS + s * 64 + 32 + p] = lo;
    }
}

// ---------------------------------------------------------------------------
// Stage 1: software-pipelined MFMA GEMM (R7 structure) with XCD swizzle.
// 1-D grid of 384 blocks: xcd = bid&7, slot = bid>>3 (0..47),
// n-tile = xcd*3 + slot/16 (3 n-tiles per XCD), m-tile = slot%16.
// ---------------------------------------------------------------------------
__global__ __launch_bounds__(256) void gemm_mfma(const unsigned short* __restrict__ A,
                                                 const unsigned short* __restrict__ B,
                                                 const float* __restrict__ biasAll,
                                                 float* __restrict__ Y) {
    __shared__ __align__(16) short As[2][64 * 64];
    __shared__ __align__(16) short Bs[2][128 * 64];

    const int tid  = threadIdx.x;
    const int bid  = blockIdx.x;
    const int xcd  = bid & 7;
    const int slot = bid >> 3;                 // 0..47
    const int m0   = (slot & 15) * 64;
    const int n0   = (xcd * 3 + (slot >> 4)) * 128;
    const int lane = tid & 63;
    const int w    = tid >> 6;
    const int wm   = w & 1;
    const int wn   = w >> 1;
    const int l15  = lane & 15;
    const int quad = lane >> 4;

    f32x4 acc[2][4];
    #pragma unroll
    for (int i = 0; i < 2; ++i)
        #pragma unroll
        for (int j = 0; j < 4; ++j)
            acc[i][j] = (f32x4){0.f, 0.f, 0.f, 0.f};

    auto stage = [&](int it, int buf) {
        const int kbase = it * 64;
        #pragma unroll
        for (int t = 0; t < 2; ++t) {
            int idx = t * 256 + tid;
            int r = idx >> 3, c = idx & 7;
            int cc = c ^ (r & 7);
            const unsigned short* ga = A + (size_t)(m0 + r) * KPHYS + kbase + cc * 8;
            __builtin_amdgcn_global_load_lds(
                (const __attribute__((address_space(1))) unsigned int*)ga,
                (__attribute__((address_space(3))) unsigned int*)&As[buf][idx * 8], 16, 0, 0);
        }
        #pragma unroll
        for (int t = 0; t < 4; ++t) {
            int idx = t * 256 + tid;
            int r = idx >> 3, c = idx & 7;
            int cc = c ^ (r & 7);
            const unsigned short* gb = B + (size_t)(n0 + r) * KPHYS + kbase + cc * 8;
            __builtin_amdgcn_global_load_lds(
                (const __attribute__((address_space(1))) unsigned int*)gb,
                (__attribute__((address_space(3))) unsigned int*)&Bs[buf][idx * 8], 16, 0, 0);
        }
    };

    stage(0, 0);

    for (int it = 0; it < 16; ++it) {
        __syncthreads();
        if (it + 1 < 16) stage(it + 1, (it + 1) & 1);

        const short* as = As[it & 1];
        const short* bs = Bs[it & 1];
        short8 ah[2], al[2], bh[4], bl[4];
        #pragma unroll
        for (int mt = 0; mt < 2; ++mt) {
            int rA = wm * 32 + mt * 16 + l15;
            int ch = quad ^ (rA & 7);
            int cl = (4 + quad) ^ (rA & 7);
            ah[mt] = *(const short8*)&as[(rA * 8 + ch) * 8];
            al[mt] = *(const short8*)&as[(rA * 8 + cl) * 8];
        }
        #pragma unroll
        for (int nt = 0; nt < 4; ++nt) {
            int rB = wn * 64 + nt * 16 + l15;
            int ch = quad ^ (rB & 7);
            int cl = (4 + quad) ^ (rB & 7);
            bh[nt] = *(const short8*)&bs[(rB * 8 + ch) * 8];
            bl[nt] = *(const short8*)&bs[(rB * 8 + cl) * 8];
        }
        #pragma unroll
        for (int mt = 0; mt < 2; ++mt)
            #pragma unroll
            for (int nt = 0; nt < 4; ++nt) {
                acc[mt][nt] = __builtin_amdgcn_mfma_f32_16x16x32_bf16(
                    ah[mt], bh[nt], acc[mt][nt], 0, 0, 0);
                acc[mt][nt] = __builtin_amdgcn_mfma_f32_16x16x32_bf16(
                    ah[mt], bl[nt], acc[mt][nt], 0, 0, 0);
                acc[mt][nt] = __builtin_amdgcn_mfma_f32_16x16x32_bf16(
                    al[mt], bh[nt], acc[mt][nt], 0, 0, 0);
            }
    }

    // Epilogue. C/D: col = lane&15, row = quad*4 + reg  [m89-verified]
    #pragma unroll
    for (int nt = 0; nt < 4; ++nt) {
        int col = n0 + wn * 64 + nt * 16 + l15;
        float bv = biasAll[col];
        #pragma unroll
        for (int mt = 0; mt < 2; ++mt) {
            int row0 = m0 + wm * 32 + mt * 16 + quad * 4;
            #pragma unroll
            for (int r = 0; r < 4; ++r)
                Y[(size_t)(row0 + r) * NCOLS + col] = acc[mt][nt][r] + bv;
        }
    }
}

// ---------------------------------------------------------------------------
// Stage 2: fused branches (R6 structure, unchanged). One wave per row;
// moments in registers, LDS-transpose reduce, Horner per i.
// ---------------------------------------------------------------------------
#define PSTR 53

__global__ __launch_bounds__(64) void fused_attn(const float* __restrict__ Y,
                                                 float* __restrict__ out) {
    const int row = blockIdx.x;
    const int l   = threadIdx.x;
    const float* __restrict__ Yr = Y + (size_t)row * NCOLS;
    const int i0 = l * 8;

    __shared__ float part[64 * PSTR];
    __shared__ float cbuf[50];

    const float LOG2E = 1.4426950408889634f;

    float4 qf0 = *(const float4*)(Yr + i0);
    float4 qf1 = *(const float4*)(Yr + i0 + 4);
    float4 kf0 = *(const float4*)(Yr + 512 + i0);
    float4 kf1 = *(const float4*)(Yr + 512 + i0 + 4);
    float4 vf0 = *(const float4*)(Yr + 1024 + i0);
    float4 vf1 = *(const float4*)(Yr + 1024 + i0 + 4);
    float4 qt0 = *(const float4*)(Yr + 1536 + i0);
    float4 qt1 = *(const float4*)(Yr + 1536 + i0 + 4);
    float4 kt0 = *(const float4*)(Yr + 2048 + i0);
    float4 kt1 = *(const float4*)(Yr + 2048 + i0 + 4);
    float4 vt0 = *(const float4*)(Yr + 2560 + i0);
    float4 vt1 = *(const float4*)(Yr + 2560 + i0 + 4);

    float e[8];
    e[0] = __builtin_amdgcn_exp2f(qf0.x * kf0.x * LOG2E);
    e[1] = __builtin_amdgcn_exp2f(qf0.y * kf0.y * LOG2E);
    e[2] = __builtin_amdgcn_exp2f(qf0.z * kf0.z * LOG2E);
    e[3] = __builtin_amdgcn_exp2f(qf0.w * kf0.w * LOG2E);
    e[4] = __builtin_amdgcn_exp2f(qf1.x * kf1.x * LOG2E);
    e[5] = __builtin_amdgcn_exp2f(qf1.y * kf1.y * LOG2E);
    e[6] = __builtin_amdgcn_exp2f(qf1.z * kf1.z * LOG2E);
    e[7] = __builtin_amdgcn_exp2f(qf1.w * kf1.w * LOG2E);
    float psum = ((e[0] + e[1]) + (e[2] + e[3])) + ((e[4] + e[5]) + (e[6] + e[7]));
    #pragma unroll
    for (int off = 32; off; off >>= 1) psum += __shfl_xor(psum, off);
    const float invS = 1.0f / psum;

    float k[8] = {kt0.x, kt0.y, kt0.z, kt0.w, kt1.x, kt1.y, kt1.z, kt1.w};
    float v[8] = {vt0.x, vt0.y, vt0.z, vt0.w, vt1.x, vt1.y, vt1.z, vt1.w};
    float kp[8] = {1.f, 1.f, 1.f, 1.f, 1.f, 1.f, 1.f, 1.f};
    float* myrow = &part[l * PSTR];
    #pragma unroll
    for (int p = 0; p < 25; ++p) {
        float n = ((kp[0] + kp[1]) + (kp[2] + kp[3])) +
                  ((kp[4] + kp[5]) + (kp[6] + kp[7]));
        float m = fmaf(kp[7], v[7], fmaf(kp[6], v[6],
                  fmaf(kp[5], v[5], fmaf(kp[4], v[4],
                  fmaf(kp[3], v[3], fmaf(kp[2], v[2],
                  fmaf(kp[1], v[1], kp[0] * v[0])))))));
        myrow[p]      = m;
        myrow[25 + p] = n;
        #pragma unroll
        for (int j = 0; j < 8; ++j) kp[j] *= k[j];
    }
    __syncthreads();

    if (l < 50) {
        float s = 0.f;
        #pragma unroll
        for (int i = 0; i < 64; ++i) s += part[i * PSTR + l];
        cbuf[l] = s * INVFACT[l < 25 ? l : l - 25];
    }
    __syncthreads();

    float q[8] = {qt0.x, qt0.y, qt0.z, qt0.w, qt1.x, qt1.y, qt1.z, qt1.w};
    float F[8], G[8];
    {
        float cf = cbuf[24], cg = cbuf[49];
        #pragma unroll
        for (int c = 0; c < 8; ++c) { F[c] = cf; G[c] = cg; }
    }
    #pragma unroll
    for (int p = 23; p >= 0; --p) {
        float cf = cbuf[p], cg = cbuf[25 + p];
        #pragma unroll
        for (int c = 0; c < 8; ++c) {
            F[c] = fmaf(F[c], q[c], cf);
            G[c] = fmaf(G[c], q[c], cg);
        }
    }

    float4 o0, o1;
    o0.x = e[0] * invS * vf0.x + F[0] / G[0];
    o0.y = e[1] * invS * vf0.y + F[1] / G[1];
    o0.z = e[2] * invS * vf0.z + F[2] / G[2];
    o0.w = e[3] * invS * vf0.w + F[3] / G[3];
    o1.x = e[4] * invS * vf1.x + F[4] / G[4];
    o1.y = e[5] * invS * vf1.y + F[5] / G[5];
    o1.z = e[6] * invS * vf1.z + F[6] / G[6];
    o1.w = e[7] * invS * vf1.w + F[7] / G[7];
    *(float4*)(out + (size_t)row * DIMD + i0)     = o0;
    *(float4*)(out + (size_t)row * DIMD + i0 + 4) = o1;
}

extern "C" void kernel_launch(void* const* d_in, const int* in_sizes, int n_in,
                              void* d_out, int out_size, void* d_ws, size_t ws_size,
                              hipStream_t stream) {
    const float* x = (const float*)d_in[0];
    PtrArgs pa;
    for (int g = 0; g < 6; ++g) {
        pa.W[g] = (const float*)d_in[1 + 2 * g];
        pa.b[g] = (const float*)d_in[2 + 2 * g];
    }

    // Workspace layout:
    //   Y:    [1024][3072] fp32  = 12,582,912 B
    //   Aph:  [1024][1024] bf16  =  2,097,152 B
    //   Bph:  [3072][1024] bf16  =  6,291,456 B
    //   bias: [3072] fp32        =     12,288 B
    char* ws = (char*)d_ws;
    float*          Y    = (float*)ws;
    unsigned short* Aph  = (unsigned short*)(ws + 12582912);
    unsigned short* Bph  = (unsigned short*)(ws + 12582912 + 2097152);
    float*          bias = (float*)(ws + 12582912 + 2097152 + 6291456);

    convert_split<<<(XN + WN) / 4 / 256, 256, 0, stream>>>(x, pa, Aph, Bph, bias);

    gemm_mfma<<<dim3(384), 256, 0, stream>>>(Aph, Bph, bias, Y);

    fused_attn<<<M_ROWS, 64, 0, stream>>>(Y, (float*)d_out);
}